// Round 10
// baseline (1019.251 us; speedup 1.0000x reference)
//
#include <hip/hip_runtime.h>
#include <math.h>

// RNNLayer: out[t] = tanh(x[t] @ Wx + b + h_{t-1} @ Wh), h_{-1} = h0
// S=128, B=128, D=1024. Inputs/outputs fp32.
//
// Round 15 = round 14 resubmitted with ONE change: __launch_bounds__(256, 1)
// on rnn_scan. Round-14's bench died at the container level (no counters);
// audit found no deadlock (tag pipeline acyclic, dbuf separated by >=1
// barrier), but DID find a latent VGPR-cap risk: ~330 VGPRs needed and no
// min-waves arg -> the backend's occupancy heuristic may cap at 256 and
// spill the weight tail (the round-4/7 trap, milder). (256,1) licenses the
// full 512-VGPR budget -> no spill. VGPR_Count in the counters is the
// verification signal (expect ~320-360; <=256 means still capped).
//
// Phase 1: xp_pers VERBATIM (verified ~275 us).
// Phase 2: rnn_scan skeleton restructure (round-14 design):
//   - 4 FULL-K waves per 256-thread block: each wave owns one 16-col tile
//     over all K=1024 (Bhi[32]+Blo[32] = 256 weight VGPRs). redS and its
//     barrier are GONE: the wave that computes a column finishes it.
//   - hS double-buffered (2 x 33 KB) -> ONE __syncthreads per step.
//   - Consumer staging: thread cu owns 4 contiguous hX cols (128 B):
//     16 x 8B bypass loads, ONE tag watch, 4x4-short transpose, 16
//     conflict-free ds_write_b64.
//   - MFMA: 64 per wave in 2 interleaved acc chains.
//   - Exchange protocol / hX layout / per-wave tags: round-8 VERBATIM.
// Workspace: tags 32 KB @0 (memset), hX 512 KB @32768.

#define DIM 1024
#define BATCH 128
#define SEQ 128
#define BD (BATCH * DIM)
#define NBLK 128
#define HSTR 1032     // LDS row stride in ushorts (bank spread)
#define FLAGSTR 16    // uints per tag slot (64 B)
#define XNB 256       // xp blocks
#define HXGRP 16384   // ushorts per hX group slab (16 rows x 1024 cols)

typedef __attribute__((ext_vector_type(8))) short bf16x8;
typedef __attribute__((ext_vector_type(4))) float f32x4;

static __device__ __forceinline__ unsigned short f2bf_rne(float f) {
    unsigned u = __builtin_bit_cast(unsigned, f);
    unsigned r = (u + 0x7FFFu + ((u >> 16) & 1u)) >> 16;
    return (unsigned short)r;
}
static __device__ __forceinline__ float bf2f(unsigned short h) {
    return __builtin_bit_cast(float, ((unsigned)h) << 16);
}

// fp32 pair -> bf16 hi (truncation) + lo (rne of residual); hi+lo ~ f to 2^-17
static __device__ __forceinline__ void split_pair(
    unsigned long long v, unsigned& hp, unsigned& lp)
{
    const unsigned u0 = (unsigned)v;
    const unsigned u1 = (unsigned)(v >> 32);
    const float f0 = __builtin_bit_cast(float, u0);
    const float f1 = __builtin_bit_cast(float, u1);
    hp = (u0 >> 16) | (u1 & 0xFFFF0000u);
    const float r0 = f0 - __builtin_bit_cast(float, u0 & 0xFFFF0000u);
    const float r1 = f1 - __builtin_bit_cast(float, u1 & 0xFFFF0000u);
    lp = (unsigned)f2bf_rne(r0) | ((unsigned)f2bf_rne(r1) << 16);
}

// ---------------------------------------------------------------------------
// Phase 1: persistent xp GEMM (verified, verbatim).
// ---------------------------------------------------------------------------
__global__ __launch_bounds__(512) void xp_pers(
    const float* __restrict__ x,
    const float* __restrict__ Wx,
    const float* __restrict__ bias,
    float* __restrict__ out)
{
    __shared__ unsigned short hHi[16 * HSTR];
    __shared__ unsigned short hLo[16 * HSTR];
    __shared__ f32x4 redS[256];

    const int tid = threadIdx.x;
    const int bid = blockIdx.x;
    const int g   = bid & 15;        // (tg,bt)
    const int ct  = bid >> 4;        // 0..15
    const int tg  = g >> 3;
    const int bt  = g & 7;
    const int B0  = bt * 16;
    const int Cb  = ct * 64;
    const int NT  = SEQ / 2;

    const int w = tid >> 6;
    const int l = tid & 63;
    const int n = l & 15;
    const int q = l >> 4;
    const int cb = Cb + (w >> 1) * 16;
    const int K0 = (w & 1) * 512;

    bf16x8 Bhi[16], Blo[16];
    #pragma unroll
    for (int s = 0; s < 16; ++s) {
        bf16x8 hi, lo;
        #pragma unroll
        for (int j = 0; j < 8; ++j) {
            const int k = K0 + 32 * s + q * 8 + j;
            const float wv = Wx[(size_t)k * DIM + cb + n];
            const unsigned short h16 = f2bf_rne(wv);
            hi[j] = (short)h16;
            lo[j] = (short)f2bf_rne(wv - bf2f(h16));
        }
        Bhi[s] = hi;
        Blo[s] = lo;
    }
    const float bv = bias[cb + n];

    const int sr = tid >> 5;    // staging: row 0..15 (32 threads per row)
    const int su = tid & 31;    // staging: ulong lane within row

    {
        const float* xT = x + (size_t)(tg * NT) * BD + (size_t)B0 * DIM;
        const unsigned long long* srow =
            (const unsigned long long*)(xT + (size_t)sr * DIM);
        unsigned short* dh = &hHi[sr * HSTR];
        unsigned short* dl = &hLo[sr * HSTR];
        #pragma unroll
        for (int i = 0; i < 16; ++i) {
            unsigned hp, lp;
            split_pair(srow[su + 32 * i], hp, lp);
            *(unsigned*)(dh + 2 * (su + 32 * i)) = hp;
            *(unsigned*)(dl + 2 * (su + 32 * i)) = lp;
        }
    }

    for (int tt = 0; tt < NT; ++tt) {
        const int t = tg * NT + tt;
        float* outT = out + (size_t)t * BD;

        unsigned long long xr[16];
        if (tt + 1 < NT) {
            const float* xN = x + (size_t)(t + 1) * BD + (size_t)B0 * DIM;
            const unsigned long long* srow =
                (const unsigned long long*)(xN + (size_t)sr * DIM);
            #pragma unroll
            for (int i = 0; i < 16; ++i) xr[i] = srow[su + 32 * i];
        }

        __syncthreads();   // B1: LDS tile tt ready; redS consumed

        f32x4 acc = {0.f, 0.f, 0.f, 0.f};
        {
            const unsigned short* rh = &hHi[(l & 15) * HSTR + K0];
            const unsigned short* rl = &hLo[(l & 15) * HSTR + K0];
            #pragma unroll
            for (int s = 0; s < 16; ++s) {
                const bf16x8 ah = *(const bf16x8*)(rh + 32 * s + 8 * q);
                const bf16x8 al = *(const bf16x8*)(rl + 32 * s + 8 * q);
                acc = __builtin_amdgcn_mfma_f32_16x16x32_bf16(ah, Bhi[s], acc, 0, 0, 0);
                acc = __builtin_amdgcn_mfma_f32_16x16x32_bf16(al, Bhi[s], acc, 0, 0, 0);
                acc = __builtin_amdgcn_mfma_f32_16x16x32_bf16(ah, Blo[s], acc, 0, 0, 0);
            }
        }

        if (w & 1) redS[(w >> 1) * 64 + l] = acc;
        __syncthreads();   // B2: all LDS reads of tile tt done

        if (!(w & 1)) {
            const f32x4 p = redS[(w >> 1) * 64 + l];
            #pragma unroll
            for (int i = 0; i < 4; ++i)
                outT[(size_t)(B0 + q * 4 + i) * DIM + cb + n] = acc[i] + p[i] + bv;
        }

        if (tt + 1 < NT) {
            unsigned short* dh = &hHi[sr * HSTR];
            unsigned short* dl = &hLo[sr * HSTR];
            #pragma unroll
            for (int i = 0; i < 16; ++i) {
                unsigned hp, lp;
                split_pair(xr[i], hp, lp);
                *(unsigned*)(dh + 2 * (su + 32 * i)) = hp;
                *(unsigned*)(dl + 2 * (su + 32 * i)) = lp;
            }
        }
    }
}

// ---------------------------------------------------------------------------
// Phase 2: persistent scan, 4 full-K waves, 1 barrier/step, dbuf LDS.
// Block: bt = bid&7 (XCD-affine group), ct = bid>>3. Wave w (0..3) owns
// col-tile cb = ct*64 + w*16 over ALL K. Tag slot = bt*64 + global col-tile.
// __launch_bounds__(256, 1): min 1 wave/EU -> full 512-VGPR budget, no cap.
// ---------------------------------------------------------------------------
__global__ __launch_bounds__(256, 1) void rnn_scan(
    const float* __restrict__ h0,
    const float* __restrict__ Wh,
    float* out,
    unsigned* tags,
    unsigned short* hX)
{
    __shared__ unsigned short hS[2][16 * HSTR];   // 66 KB double-buffered h

    const int tid = threadIdx.x;
    const int p   = blockIdx.x;
    const int bt  = p & 7;           // XCD-affine: group bt lives on one XCD
    const int ct  = p >> 3;
    const int B0  = bt * 16;
    const int Cb  = ct * 64;

    const int w = tid >> 6;          // 0..3: col-tile
    const int l = tid & 63;
    const int n = l & 15;
    const int q = l >> 4;
    const int cb = Cb + w * 16;

    // ---- resident Wh fragments (bf16 hi + lo), FULL K (256 VGPRs) ----
    bf16x8 Bhi[32], Blo[32];
    #pragma unroll
    for (int s = 0; s < 32; ++s) {
        bf16x8 hi, lo;
        #pragma unroll
        for (int j = 0; j < 8; ++j) {
            const int k = 32 * s + q * 8 + j;
            const float wv = Wh[(size_t)k * DIM + cb + n];
            const unsigned short h16 = f2bf_rne(wv);
            hi[j] = (short)h16;
            lo[j] = (short)f2bf_rne(wv - bf2f(h16));
        }
        Bhi[s] = hi;
        Blo[s] = lo;
    }

    // consumer staging: thread cu owns hX cols 4cu..4cu+3 (128 contiguous B)
    const int cu = tid;
    const unsigned* tgp = &tags[(bt * 64 + (cu >> 2)) * FLAGSTR];
    const int myslot = bt * 64 + ct * 4 + w;

    // t==0 staging: 16 threads per row
    const int sr = tid >> 4;
    const int su = tid & 15;

    for (int t = 0; t < SEQ; ++t) {
        float* outT = out + (size_t)t * BD;

        // xp prefetch (xp_pers completed; latency hides under spin/staging)
        float xpv[4];
        #pragma unroll
        for (int i = 0; i < 4; ++i)
            xpv[i] = __builtin_nontemporal_load(
                &outT[(size_t)(B0 + q * 4 + i) * DIM + cb + n]);

        // ---- stage h tile into hS[t&1] ----
        if (t == 0) {
            const float* hsrc = h0 + (size_t)B0 * DIM;
            const unsigned long long* srow =
                (const unsigned long long*)(hsrc + (size_t)sr * DIM);
            unsigned short* drow = &hS[0][sr * HSTR];
            #pragma unroll
            for (int i = 0; i < 32; ++i) {
                const unsigned long long v = srow[su + 16 * i];
                const float f0 = __builtin_bit_cast(float, (unsigned)(v & 0xFFFFFFFFull));
                const float f1 = __builtin_bit_cast(float, (unsigned)(v >> 32));
                const unsigned pk =
                    (unsigned)f2bf_rne(f0) | ((unsigned)f2bf_rne(f1) << 16);
                *(unsigned*)(drow + 2 * (su + 16 * i)) = pk;
            }
        } else {
            // spin my single tag (h_{t-1} cols 4cu..4cu+3 published)
            const unsigned need = (unsigned)t;
            while (__hip_atomic_load(tgp, __ATOMIC_RELAXED,
                                     __HIP_MEMORY_SCOPE_AGENT) < need)
                __builtin_amdgcn_s_sleep(1);
            asm volatile("" ::: "memory");   // pin data loads after the spin

            // 16 x 8B bypass loads: L[c][qd] = rows 4qd..4qd+3 of col 4cu+c
            const unsigned short* gX = hX + (size_t)((t - 1) & 1) * (8 * HXGRP)
                                          + (size_t)bt * HXGRP;
            unsigned long long L[4][4];
            #pragma unroll
            for (int c = 0; c < 4; ++c)
                #pragma unroll
                for (int qd = 0; qd < 4; ++qd)
                    L[c][qd] = __hip_atomic_load(
                        (const unsigned long long*)(gX + (size_t)(4 * cu + c) * 16 + qd * 4),
                        __ATOMIC_RELAXED, __HIP_MEMORY_SCOPE_AGENT);

            // 4x4-short transpose -> row-major LDS, 16 x ds_write_b64
            unsigned short* dst = &hS[t & 1][0];
            #pragma unroll
            for (int qd = 0; qd < 4; ++qd) {
                #pragma unroll
                for (int rr = 0; rr < 4; ++rr) {
                    const int r = 4 * qd + rr;
                    const int sh = 16 * rr;
                    const unsigned long long row =
                          ((L[0][qd] >> sh) & 0xFFFFull)
                        | (((L[1][qd] >> sh) & 0xFFFFull) << 16)
                        | (((L[2][qd] >> sh) & 0xFFFFull) << 32)
                        | (((L[3][qd] >> sh) & 0xFFFFull) << 48);
                    *(unsigned long long*)&dst[r * HSTR + 4 * cu] = row;
                }
            }
        }

        __syncthreads();   // THE barrier: hS[t&1] staged; prev buf reads done

        // ---- MFMA: full K, 2 interleaved acc chains ----
        f32x4 a0 = {0.f, 0.f, 0.f, 0.f};
        f32x4 a1 = {0.f, 0.f, 0.f, 0.f};
        {
            const unsigned short* hrow = &hS[t & 1][(l & 15) * HSTR];
            #pragma unroll
            for (int s = 0; s < 32; s += 2) {
                const bf16x8 x0 = *(const bf16x8*)(hrow + 32 * s + 8 * q);
                const bf16x8 x1 = *(const bf16x8*)(hrow + 32 * (s + 1) + 8 * q);
                a0 = __builtin_amdgcn_mfma_f32_16x16x32_bf16(x0, Bhi[s], a0, 0, 0, 0);
                a1 = __builtin_amdgcn_mfma_f32_16x16x32_bf16(x1, Bhi[s + 1], a1, 0, 0, 0);
                a0 = __builtin_amdgcn_mfma_f32_16x16x32_bf16(x0, Blo[s], a0, 0, 0, 0);
                a1 = __builtin_amdgcn_mfma_f32_16x16x32_bf16(x1, Blo[s + 1], a1, 0, 0, 0);
            }
        }

        // ---- epilogue: this wave owns the whole column tile ----
        const float v0 = tanhf(a0[0] + a1[0] + xpv[0]);
        const float v1 = tanhf(a0[1] + a1[1] + xpv[1]);
        const float v2 = tanhf(a0[2] + a1[2] + xpv[2]);
        const float v3 = tanhf(a0[3] + a1[3] + xpv[3]);

        if (t < SEQ - 1) {
            // bf16 side-channel store, wave-local drain, per-wave tag post
            const unsigned p0 = (unsigned)f2bf_rne(v0) | ((unsigned)f2bf_rne(v1) << 16);
            const unsigned p1 = (unsigned)f2bf_rne(v2) | ((unsigned)f2bf_rne(v3) << 16);
            unsigned short* gW = hX + (size_t)(t & 1) * (8 * HXGRP)
                                    + (size_t)bt * HXGRP;
            __hip_atomic_store(
                (unsigned long long*)(gW + (size_t)(cb + n) * 16 + q * 4),
                (unsigned long long)p0 | ((unsigned long long)p1 << 32),
                __ATOMIC_RELAXED, __HIP_MEMORY_SCOPE_AGENT);
            // drain THIS WAVE's stores to the coherence point (wave-scoped)
            asm volatile("s_waitcnt vmcnt(0)" ::: "memory");
            if (l == 0)
                __hip_atomic_store(&tags[myslot * FLAGSTR], (unsigned)(t + 1),
                                   __ATOMIC_RELAXED, __HIP_MEMORY_SCOPE_AGENT);
        }

        // fp32 output stores: off the exchange critical path
        __builtin_nontemporal_store(v0, &outT[(size_t)(B0 + q * 4 + 0) * DIM + cb + n]);
        __builtin_nontemporal_store(v1, &outT[(size_t)(B0 + q * 4 + 1) * DIM + cb + n]);
        __builtin_nontemporal_store(v2, &outT[(size_t)(B0 + q * 4 + 2) * DIM + cb + n]);
        __builtin_nontemporal_store(v3, &outT[(size_t)(B0 + q * 4 + 3) * DIM + cb + n]);
        // no tail barrier: the next step's single barrier separates this
        // step's hS reads from staging writes two steps out (dbuf argument).
    }
}

// ---------------------------------------------------------------------------
extern "C" void kernel_launch(void* const* d_in, const int* in_sizes, int n_in,
                              void* d_out, int out_size, void* d_ws, size_t ws_size,
                              hipStream_t stream) {
    const float* x  = (const float*)d_in[0];   // [S,B,D]
    const float* h0 = (const float*)d_in[1];   // [B,D]
    const float* Wx = (const float*)d_in[2];   // [D,D]
    const float* Wh = (const float*)d_in[3];   // [D,D]
    const float* b  = (const float*)d_in[4];   // [D]
    float* out = (float*)d_out;                // [S,B,D]
    unsigned* tags = (unsigned*)d_ws;                             // 32 KB
    unsigned short* hX = (unsigned short*)((char*)d_ws + 32768);  // 512 KB

    hipMemsetAsync(d_ws, 0, 512 * FLAGSTR * sizeof(unsigned), stream);

    xp_pers<<<dim3(XNB), dim3(512), 0, stream>>>(x, Wx, b, out);

    rnn_scan<<<dim3(NBLK), dim3(256), 0, stream>>>(h0, Wh, out, tags, hX);
}